// Round 9
// baseline (97.812 us; speedup 1.0000x reference)
//
#include <hip/hip_runtime.h>

// GCNAggregator — R9 DIAGNOSTIC round (expect dur regression; info purchase).
// R8 analysis: 3-node chain = prep(~8) + colcount(hidden) + gather(~29-31?) +
// ~1-2 overhead. To pin gather's true duration, launch the (idempotent) gather
// node 4x: g = (total - 40)/3. Warm repeats also bound the best achievable
// rate for this 1-KiB-granule scatter-gather pattern.
//
// Structure otherwise identical to R8:
//   N1 prep_feat : zero colcnt + convert feat->bf16 half
//   N2 prep_noise: convert noise->bf16 half + colcount
//   N3..N6 gather: one dwordx4/lane/k from packed table [U][1KiB]

#define B_ 4096
#define K_ 32
#define U_ 16384
#define D_ 256
#define HALF_SLOTS (U_ * D_ / 8)       // 524288 uint4 slots per table

typedef unsigned int uint4n __attribute__((ext_vector_type(4)));

__device__ __forceinline__ unsigned bf16_rne(float x) {
    const unsigned u = __float_as_uint(x);
    return (u + 0x7FFFu + ((u >> 16) & 1u)) >> 16;
}
__device__ __forceinline__ unsigned pack2(float lo, float hi) {
    return bf16_rne(lo) | (bf16_rne(hi) << 16);
}
__device__ __forceinline__ float blo(unsigned v) { return __uint_as_float(v << 16); }
__device__ __forceinline__ float bhi(unsigned v) { return __uint_as_float(v & 0xFFFF0000u); }

__device__ __forceinline__ void conv_slot(const float4* __restrict__ src,
                                          uint4n* __restrict__ packed,
                                          int t, int half_off) {
    const int u = t >> 5;
    const int s = t & 31;
    const float4 a = src[u * (D_ / 4) + s * 2];
    const float4 b = src[u * (D_ / 4) + s * 2 + 1];
    uint4n o;
    o.x = pack2(a.x, a.y);
    o.y = pack2(a.z, a.w);
    o.z = pack2(b.x, b.y);
    o.w = pack2(b.z, b.w);
    __builtin_nontemporal_store(o, &packed[u * 64 + half_off + s]);
}

__global__ __launch_bounds__(256) void gcn_prep_feat(const float4* __restrict__ feat,
                                                     uint4n* __restrict__ packed,
                                                     int* __restrict__ colcnt) {
    const int gid = blockIdx.x * 256 + threadIdx.x;
    if (gid < U_) colcnt[gid] = 0;
    conv_slot(feat, packed, gid, 0);
}

__global__ __launch_bounds__(256) void gcn_prep_noise(const int* __restrict__ idx,
                                                      const float4* __restrict__ noise,
                                                      uint4n* __restrict__ packed,
                                                      int* __restrict__ colcnt) {
    const int gid = blockIdx.x * 256 + threadIdx.x;
    conv_slot(noise, packed, gid, 32);

    const int wg = gid >> 6;
    if (wg < B_) {
        const int lane = threadIdx.x & 63;
        const int kk = lane & 31;
        const int u = idx[wg * K_ + kk];
        bool dup = false;
        #pragma unroll
        for (int j = 0; j < K_; ++j) {
            const int uj = __shfl(u, j);
            if (j < kk && uj == u) dup = true;
        }
        if (lane < 32 && !dup) atomicAdd(&colcnt[u], 1);
    }
}

__global__ __launch_bounds__(256) void gcn_gather(const int* __restrict__ idx,
                                                  const uint4n* __restrict__ packed,
                                                  const int* __restrict__ colcnt,
                                                  float4* __restrict__ out) {
    const int row = blockIdx.x * 4 + (threadIdx.x >> 6);
    const int lane = threadIdx.x & 63;

    const int kk = lane & 31;
    const int u = idx[row * K_ + kk];

    bool dup = false;
    #pragma unroll
    for (int j = 0; j < K_; ++j) {
        const int uj = __shfl(u, j);
        if (j < kk && uj == u) dup = true;
    }
    const int rowcnt = __popcll(__ballot(!dup) & 0xFFFFFFFFull);

    float w = 0.0f;
    if (!dup) w = rsqrtf((float)(rowcnt * colcnt[u]));

    int us[K_]; float wk[K_];
    #pragma unroll
    for (int k = 0; k < K_; ++k) {
        us[k] = __builtin_amdgcn_readlane(u, k);
        wk[k] = __uint_as_float(
            (unsigned)__builtin_amdgcn_readlane((int)__float_as_uint(w), k));
    }

    float a0 = 0.f, a1 = 0.f, a2 = 0.f, a3 = 0.f;
    float a4 = 0.f, a5 = 0.f, a6 = 0.f, a7 = 0.f;

    #pragma unroll
    for (int k = 0; k < K_; ++k) {
        const uint4n v = packed[us[k] * 64 + lane];
        const float wkk = wk[k];
        a0 = fmaf(wkk, blo(v.x), a0);
        a1 = fmaf(wkk, bhi(v.x), a1);
        a2 = fmaf(wkk, blo(v.y), a2);
        a3 = fmaf(wkk, bhi(v.y), a3);
        a4 = fmaf(wkk, blo(v.z), a4);
        a5 = fmaf(wkk, bhi(v.z), a5);
        a6 = fmaf(wkk, blo(v.w), a6);
        a7 = fmaf(wkk, bhi(v.w), a7);
    }

    const int base = (lane < 32)
        ? (row * (D_ / 4) + lane * 2)
        : (B_ * (D_ / 4) + row * (D_ / 4) + (lane - 32) * 2);
    out[base]     = make_float4(a0, a1, a2, a3);
    out[base + 1] = make_float4(a4, a5, a6, a7);
}

extern "C" void kernel_launch(void* const* d_in, const int* in_sizes, int n_in,
                              void* d_out, int out_size, void* d_ws, size_t ws_size,
                              hipStream_t stream) {
    const int*    idx   = (const int*)d_in[0];        // [B,K] int32
    const float4* feat  = (const float4*)d_in[1];     // [U,D] f32
    const float4* noise = (const float4*)d_in[2];     // [U,D] f32
    float4*       out   = (float4*)d_out;             // [2*B, D] f32

    uint4n* packed = (uint4n*)d_ws;                   // 16 MiB packed bf16 table
    int*    colcnt = (int*)((char*)d_ws + 32u * 1024 * 1024);  // 64 KiB

    gcn_prep_feat <<<HALF_SLOTS / 256, 256, 0, stream>>>(feat, packed, colcnt);
    gcn_prep_noise<<<HALF_SLOTS / 256, 256, 0, stream>>>(idx, noise, packed, colcnt);
    // DIAGNOSTIC: gather x4 (idempotent). g = (total - 40)/3.
    gcn_gather    <<<B_ / 4,          256, 0, stream>>>(idx, packed, colcnt, out);
    gcn_gather    <<<B_ / 4,          256, 0, stream>>>(idx, packed, colcnt, out);
    gcn_gather    <<<B_ / 4,          256, 0, stream>>>(idx, packed, colcnt, out);
    gcn_gather    <<<B_ / 4,          256, 0, stream>>>(idx, packed, colcnt, out);
}

// Round 10
// 44.991 us; speedup vs baseline: 2.1740x; 2.1740x over previous
//
#include <hip/hip_runtime.h>

// GCNAggregator: B=4096 rows, K=32 neighbor indices into U=16384 node tables
// of D=256 f32. Set-semantics mask, symmetric GCN norm.
//   out_feats[b,:] = (1/sqrt(rowcnt_b)) * sum_{unique u in b} feat[u,:]/sqrt(colcnt_u)
// d_out = [to_feats (B*D) | to_noise (B*D)] f32.
//
// R10: discriminate "prep slow" vs "gather1 cold". Changes vs R8:
//  - regular stores (no nontemporal) so packed lines stay in L2/L3
//  - ONE merged prep kernel for both tables (was 2)
//  - colcount moved BEFORE prep; prep pre-scales rows by 1/sqrt(colcnt) so
//    gather needs no colcnt reads and no per-k weight broadcast (dup-skip via
//    wave-uniform ballot mask; 1/sqrt(rowcnt) applied once at the end).
// Chain: Z(zero colcnt) -> C(colcount) -> P(convert+scale) -> G(gather).
// Packed table [U][1 KiB] = {feat 512B | noise 512B} bf16.

#define B_ 4096
#define K_ 32
#define U_ 16384
#define D_ 256
#define HALF_SLOTS (U_ * D_ / 8)       // 524288 8-dim slots per table

typedef unsigned int uint4n __attribute__((ext_vector_type(4)));

__device__ __forceinline__ unsigned bf16_rne(float x) {
    const unsigned u = __float_as_uint(x);
    return (u + 0x7FFFu + ((u >> 16) & 1u)) >> 16;
}
__device__ __forceinline__ unsigned pack2(float lo, float hi) {
    return bf16_rne(lo) | (bf16_rne(hi) << 16);
}
__device__ __forceinline__ float blo(unsigned v) { return __uint_as_float(v << 16); }
__device__ __forceinline__ float bhi(unsigned v) { return __uint_as_float(v & 0xFFFF0000u); }

// Z: zero colcnt. 16 blocks x 256 thr x int4.
__global__ __launch_bounds__(256) void gcn_zero(int4* __restrict__ colcnt4) {
    colcnt4[blockIdx.x * 256 + threadIdx.x] = make_int4(0, 0, 0, 0);
}

// C: per-row dedup (wave-local), atomicAdd unique (b,u) into colcnt[u].
__global__ __launch_bounds__(256) void gcn_colcount(const int* __restrict__ idx,
                                                    int* __restrict__ colcnt) {
    const int row = blockIdx.x * 4 + (threadIdx.x >> 6);
    const int lane = threadIdx.x & 63;
    const int kk = lane & 31;                // lanes 32..63 mirror 0..31
    const int u = idx[row * K_ + kk];
    bool dup = false;
    #pragma unroll
    for (int j = 0; j < K_; ++j) {
        const int uj = __shfl(u, j);
        if (j < kk && uj == u) dup = true;   // first occurrence wins
    }
    if (lane < 32 && !dup) atomicAdd(&colcnt[u], 1);
}

// P: convert BOTH tables to bf16, pre-scaled by 1/sqrt(colcnt[u]).
// 4096 blocks x 256 thr; thread t handles one 8-dim slot.
// packed row u = 64 uint4: slots 0..31 feat dims, 32..63 noise dims.
__global__ __launch_bounds__(256) void gcn_prep(const float4* __restrict__ feat,
                                                const float4* __restrict__ noise,
                                                const int* __restrict__ colcnt,
                                                uint4n* __restrict__ packed) {
    const int t = blockIdx.x * 256 + threadIdx.x;
    const bool isNoise = t >= HALF_SLOTS;
    const int tt = isNoise ? t - HALF_SLOTS : t;
    const int u = tt >> 5;                   // 32 slots of 8 dims per u
    const int s = tt & 31;
    const float4* src = isNoise ? noise : feat;

    const float cf = rsqrtf((float)colcnt[u]);   // unreferenced u: inf, never read
    const float4 a = src[u * (D_ / 4) + s * 2];
    const float4 b = src[u * (D_ / 4) + s * 2 + 1];
    uint4n o;
    o.x = pack2(a.x * cf, a.y * cf);
    o.y = pack2(a.z * cf, a.w * cf);
    o.z = pack2(b.x * cf, b.y * cf);
    o.w = pack2(b.z * cf, b.w * cf);
    packed[u * 64 + (isNoise ? 32 : 0) + s] = o;
}

// G: gather. One wave per row; lanes 0..31 feat dims, 32..63 noise dims.
// Dup slots skipped via wave-uniform ballot mask; 1/sqrt(rowcnt) at the end.
__global__ __launch_bounds__(256) void gcn_gather(const int* __restrict__ idx,
                                                  const uint4n* __restrict__ packed,
                                                  float4* __restrict__ out) {
    const int row = blockIdx.x * 4 + (threadIdx.x >> 6);
    const int lane = threadIdx.x & 63;

    const int kk = lane & 31;
    const int u = idx[row * K_ + kk];

    bool dup = false;
    #pragma unroll
    for (int j = 0; j < K_; ++j) {
        const int uj = __shfl(u, j);
        if (j < kk && uj == u) dup = true;
    }
    const unsigned uniq = (unsigned)(__ballot(!dup) & 0xFFFFFFFFull); // wave-uniform
    const float rowfac = rsqrtf((float)__popc(uniq));

    int us[K_];
    #pragma unroll
    for (int k = 0; k < K_; ++k)
        us[k] = __builtin_amdgcn_readlane(u, k);   // SGPR broadcast

    float a0 = 0.f, a1 = 0.f, a2 = 0.f, a3 = 0.f;
    float a4 = 0.f, a5 = 0.f, a6 = 0.f, a7 = 0.f;

    #pragma unroll
    for (int k = 0; k < K_; ++k) {
        if ((uniq >> k) & 1u) {              // wave-uniform branch, skips dups
            const uint4n v = packed[us[k] * 64 + lane];
            a0 += blo(v.x); a1 += bhi(v.x);
            a2 += blo(v.y); a3 += bhi(v.y);
            a4 += blo(v.z); a5 += bhi(v.z);
            a6 += blo(v.w); a7 += bhi(v.w);
        }
    }

    // lanes 0..31: to_feats[row][lane*8..+8); lanes 32..63: to_noise same dims
    const int base = (lane < 32)
        ? (row * (D_ / 4) + lane * 2)
        : (B_ * (D_ / 4) + row * (D_ / 4) + (lane - 32) * 2);
    out[base]     = make_float4(a0 * rowfac, a1 * rowfac, a2 * rowfac, a3 * rowfac);
    out[base + 1] = make_float4(a4 * rowfac, a5 * rowfac, a6 * rowfac, a7 * rowfac);
}

extern "C" void kernel_launch(void* const* d_in, const int* in_sizes, int n_in,
                              void* d_out, int out_size, void* d_ws, size_t ws_size,
                              hipStream_t stream) {
    const int*    idx   = (const int*)d_in[0];        // [B,K] int32
    const float4* feat  = (const float4*)d_in[1];     // [U,D] f32
    const float4* noise = (const float4*)d_in[2];     // [U,D] f32
    float4*       out   = (float4*)d_out;             // [2*B, D] f32

    uint4n* packed = (uint4n*)d_ws;                   // 16 MiB packed bf16 table
    int*    colcnt = (int*)((char*)d_ws + 32u * 1024 * 1024);  // 64 KiB

    gcn_zero    <<<U_ / 1024,           256, 0, stream>>>((int4*)colcnt);
    gcn_colcount<<<B_ / 4,              256, 0, stream>>>(idx, colcnt);
    gcn_prep    <<<2 * HALF_SLOTS / 256, 256, 0, stream>>>(feat, noise, colcnt, packed);
    gcn_gather  <<<B_ / 4,              256, 0, stream>>>(idx, packed, out);
}